// Round 3
// baseline (999.729 us; speedup 1.0000x reference)
//
#include <hip/hip_runtime.h>
#include <stdint.h>

// ---------------------------------------------------------------------------
// NodeDropout: drop-set = jax.random.permutation(key(42), 200000)[:20000]
// (partitionable threefry), keep edge unless BOTH endpoints dropped,
// stable-compact kept edges, -1 tail.
// Single-pass edge compaction via ticket-ordered decoupled lookback.
// ---------------------------------------------------------------------------

#define N_NODES   200000
#define N_DROP    20000
#define NEDGE     20000000
#define NBIN      65536
#define NWORDS_ND 6250          // 200000/32

// fused edge-pass geometry
#define FB_T      256
#define FB_VEC    4
#define FB_IT     4
#define FB_EDGES  (FB_T*FB_VEC*FB_IT)               // 4096
#define FB_NB     ((NEDGE + FB_EDGES - 1)/FB_EDGES) // 4883

#define VALMASK   ((1ull<<62)-1)
#define FL_AGG    1ull
#define FL_PRE    2ull

// ---- workspace layout (bytes). Zeroed region: [0, ZERO_BYTES) ----
#define OFS_HIST1   0u
#define OFS_HIST2   262144u
#define OFS_CNT1    524288u
#define OFS_SCAL    786432u     // u64[8]: 0=B 1=r 2=T 3=candCount(u32) 4=ticket(u32)
#define OFS_DESC    786496u     // FB_NB u64 lookback descriptors
#define ZERO_BYTES  825560u     // 786496 + 4883*8
#define OFS_OFFS1   825560u
#define OFS_BITS1   1087704u
#define OFS_BITS2   1887704u
#define OFS_RANK1   2687704u
#define OFS_SORT1   3487704u
#define OFS_CAND    5087704u    // 4096 u64
#define OFS_DROPB   5120472u    // 6250 u32 node drop bits
// total ~5.15 MB

struct U2pair { uint32_t a, b; };

// Threefry-2x32, 20 rounds — exact JAX/Random123 schedule.
__host__ __device__ constexpr U2pair tf2x32(uint32_t k0, uint32_t k1,
                                            uint32_t x0, uint32_t x1) {
  uint32_t ks[3] = { k0, k1, 0x1BD11BDAu ^ k0 ^ k1 };
  uint32_t v0 = x0 + ks[0];
  uint32_t v1 = x1 + ks[1];
  const int rotA[4] = {13, 15, 26, 6};
  const int rotB[4] = {17, 29, 16, 24};
  for (int i = 0; i < 5; ++i) {
    for (int j = 0; j < 4; ++j) {
      const int r = (i & 1) ? rotB[j] : rotA[j];
      v0 += v1;
      v1 = (v1 << r) | (v1 >> (32 - r));
      v1 ^= v0;
    }
    v0 += ks[(i + 1) % 3];
    v1 += ks[(i + 2) % 3] + (uint32_t)(i + 1);
  }
  return U2pair{v0, v1};
}

// Partitionable key chain from key(42) = (0,42):
//   split: keys[j] = tf(key, 0, j).  carried = keys[0], use1 = keys[1]
//   split #2 on carried: use2 = tf(carried, 0, 1)
constexpr U2pair CARRY1 = tf2x32(0u, 42u, 0u, 0u);
constexpr U2pair USE1   = tf2x32(0u, 42u, 0u, 1u);
constexpr uint32_t UK1A = USE1.a, UK1B = USE1.b;
constexpr U2pair USE2   = tf2x32(CARRY1.a, CARRY1.b, 0u, 1u);
constexpr uint32_t UK2A = USE2.a, UK2B = USE2.b;

// ---------------------------------------------------------------------------
// K1: bits1/bits2 (partitionable: bits[i] = out0^out1 of counter (0,i)) + hists.
__global__ void k_bits_hist(uint32_t* __restrict__ bits1,
                            uint32_t* __restrict__ bits2,
                            uint32_t* __restrict__ hist1,
                            uint32_t* __restrict__ hist2) {
  const int i = blockIdx.x * blockDim.x + threadIdx.x;
  if (i >= N_NODES) return;
  const U2pair r1 = tf2x32(UK1A, UK1B, 0u, (uint32_t)i);
  const U2pair r2 = tf2x32(UK2A, UK2B, 0u, (uint32_t)i);
  const uint32_t b1 = r1.a ^ r1.b;
  const uint32_t b2 = r2.a ^ r2.b;
  bits1[i] = b1;
  bits2[i] = b2;
  atomicAdd(&hist1[b1 >> 16], 1u);
  atomicAdd(&hist2[b2 >> 16], 1u);
}

// K2: dual histogram scan. Block 0: hist1 -> offs1. Block 1: hist2 + findSel.
__global__ __launch_bounds__(1024)
void k_scan_both(const uint32_t* __restrict__ hist1,
                 const uint32_t* __restrict__ hist2,
                 uint32_t* __restrict__ offs1,
                 uint64_t* __restrict__ scal) {
  const uint32_t* hist = (blockIdx.x == 0) ? hist1 : hist2;
  uint32_t* offs       = (blockIdx.x == 0) ? offs1 : nullptr;
  const int findSel    = (blockIdx.x == 0) ? 0 : 1;
  __shared__ uint32_t sums[1024];
  const int t = threadIdx.x;
  uint32_t s = 0;
  for (int j = 0; j < NBIN / 1024; ++j) s += hist[t * (NBIN / 1024) + j];
  sums[t] = s;
  __syncthreads();
  for (int d = 1; d < 1024; d <<= 1) {
    const uint32_t v = sums[t];
    const uint32_t add = (t >= d) ? sums[t - d] : 0u;
    __syncthreads();
    sums[t] = v + add;
    __syncthreads();
  }
  uint32_t run = (t == 0) ? 0u : sums[t - 1];
  for (int j = 0; j < NBIN / 1024; ++j) {
    const int b = t * (NBIN / 1024) + j;
    const uint32_t c = hist[b];
    if (offs) offs[b] = run;
    if (findSel && run <= (uint32_t)(N_DROP - 1) &&
        (uint32_t)(N_DROP - 1) < run + c) {
      scal[0] = (uint64_t)b;
      scal[1] = (uint64_t)((N_DROP - 1) - run);
    }
    run += c;
  }
}

// K3: scatter round-1 composite keys into buckets + gather round-2 candidates.
__global__ void k_scatter_cand(const uint32_t* __restrict__ bits1,
                               const uint32_t* __restrict__ bits2,
                               const uint32_t* __restrict__ offs1,
                               uint32_t* __restrict__ cnt1,
                               uint64_t* __restrict__ sort1,
                               const uint64_t* __restrict__ scal,
                               uint64_t* __restrict__ cand,
                               uint32_t* __restrict__ candCount) {
  const int i = blockIdx.x * blockDim.x + threadIdx.x;
  if (i >= N_NODES) return;
  const uint32_t k = bits1[i];
  const uint32_t b = k >> 16;
  const uint32_t slot = atomicAdd(&cnt1[b], 1u);
  sort1[offs1[b] + slot] = ((uint64_t)k << 32) | (uint32_t)i;

  const uint32_t B = (uint32_t)scal[0];
  const uint32_t k2 = bits2[i];
  if ((k2 >> 16) == B) {
    const uint32_t p = atomicAdd(candCount, 1u);
    if (p < 4096u) cand[p] = ((uint64_t)k2 << 32) | (uint32_t)i;
  }
}

// K4: rank1 (blocks 0..781) + threshold select (block 782).
__global__ void k_rank1_thresh(const uint32_t* __restrict__ bits1,
                               const uint32_t* __restrict__ offs1,
                               const uint32_t* __restrict__ hist1,
                               const uint64_t* __restrict__ sort1,
                               uint32_t* __restrict__ rank1,
                               const uint64_t* __restrict__ cand,
                               const uint32_t* __restrict__ candCount,
                               uint64_t* __restrict__ scal) {
  if (blockIdx.x == 782) {
    if (threadIdx.x != 0) return;
    const uint32_t n = *candCount;
    const uint32_t r = (uint32_t)scal[1];
    uint64_t T = 0;
    for (uint32_t a = 0; a < n; ++a) {
      const uint64_t v = cand[a];
      uint32_t c = 0;
      for (uint32_t b = 0; b < n; ++b) c += (cand[b] < v) ? 1u : 0u;
      if (c == r) { T = v; break; }
    }
    scal[2] = T;
    return;
  }
  const int i = blockIdx.x * blockDim.x + threadIdx.x;
  if (i >= N_NODES) return;
  const uint32_t k = bits1[i];
  const uint32_t b = k >> 16;
  const uint64_t me = ((uint64_t)k << 32) | (uint32_t)i;
  const uint32_t start = offs1[b];
  const uint32_t cnt = hist1[b];
  uint32_t c = 0;
  for (uint32_t s = 0; s < cnt; ++s) c += (sort1[start + s] < me) ? 1u : 0u;
  rank1[i] = start + c;
}

// K5: node drop bits. drop[i] = K2(rank1(i)) <= T.
__global__ void k_drop(const uint32_t* __restrict__ bits2,
                       const uint32_t* __restrict__ rank1,
                       const uint64_t* __restrict__ scal,
                       uint32_t* __restrict__ dropbits) {
  const int w = blockIdx.x * blockDim.x + threadIdx.x;
  if (w >= NWORDS_ND) return;
  const uint64_t T = scal[2];
  uint32_t word = 0;
  #pragma unroll 4
  for (int j = 0; j < 32; ++j) {
    const int i = w * 32 + j;
    const uint32_t jj = rank1[i];
    const uint64_t K2 = ((uint64_t)bits2[jj] << 32) | jj;
    if (K2 <= T) word |= (1u << j);
  }
  dropbits[w] = word;
}

// ---------------------------------------------------------------------------
// K6: single-pass edge compaction. Ticket-ordered decoupled lookback:
// ticket acquisition order == processing order, so all lower tickets are
// resident -> forward progress guaranteed. Kept edges staged in LDS, dumped
// as dense aligned int4 stores. Dropped edges (-1) written at reverse-indexed
// tail slots NEDGE-1-(dropExcl+j), which tile exactly [n_keep, NEDGE).
__global__ __launch_bounds__(FB_T)
void k_fused(const int* __restrict__ ei,
             const uint32_t* __restrict__ dropbits,
             uint32_t* __restrict__ ticket,
             uint64_t* __restrict__ desc,
             int* __restrict__ out) {
  __shared__ int ldsU[FB_EDGES];
  __shared__ int ldsI[FB_EDGES];
  __shared__ uint32_t wtot[FB_T / 64];
  __shared__ uint32_t sb[2];  // [0]=ticket  [1]=exclusive keep prefix
  const int t = threadIdx.x;
  const int lane = t & 63, wid = t >> 6;

  if (t == 0) sb[0] = atomicAdd(ticket, 1u);
  __syncthreads();
  const uint32_t vb = sb[0];
  const int64_t blockStart = (int64_t)vb * FB_EDGES;

  // phase 1: flags + block-local compaction into LDS
  uint32_t runBase = 0;
  for (int k = 0; k < FB_IT; ++k) {
    const int64_t e = blockStart + (int64_t)(k * (FB_T * FB_VEC) + t * FB_VEC);
    uint32_t flags = 0;
    int us[4] = {0, 0, 0, 0}, is_[4] = {0, 0, 0, 0};
    if (e < NEDGE) {
      const int4 u4 = *(const int4*)(ei + e);
      const int4 i4 = *(const int4*)(ei + NEDGE + e);
      us[0] = u4.x; us[1] = u4.y; us[2] = u4.z; us[3] = u4.w;
      is_[0] = i4.x; is_[1] = i4.y; is_[2] = i4.z; is_[3] = i4.w;
      #pragma unroll
      for (int j = 0; j < 4; ++j) {
        const uint32_t du = (dropbits[us[j] >> 5] >> (us[j] & 31)) & 1u;
        uint32_t keep = 1u;
        if (du) keep = 1u - ((dropbits[is_[j] >> 5] >> (is_[j] & 31)) & 1u);
        flags |= keep << j;
      }
    }
    const uint32_t c = __popc(flags);
    uint32_t incl = c;
    #pragma unroll
    for (int d = 1; d < 64; d <<= 1) {
      const uint32_t o = __shfl_up(incl, (unsigned)d);
      if (lane >= d) incl += o;
    }
    if (lane == 63) wtot[wid] = incl;
    __syncthreads();
    uint32_t wpref = 0, tot = 0;
    #pragma unroll
    for (int w2 = 0; w2 < FB_T / 64; ++w2) {
      const uint32_t v = wtot[w2];
      if (w2 < wid) wpref += v;
      tot += v;
    }
    uint32_t pos = runBase + wpref + incl - c;
    #pragma unroll
    for (int j = 0; j < 4; ++j) {
      if ((flags >> j) & 1u) { ldsU[pos] = us[j]; ldsI[pos] = is_[j]; ++pos; }
    }
    runBase += tot;
    __syncthreads();
  }
  const uint32_t localKeep = runBase;

  // phase 1.5: publish aggregate, wave-parallel lookback, publish inclusive
  if (wid == 0) {
    if (lane == 0) {
      const uint64_t d0 = ((vb == 0 ? FL_PRE : FL_AGG) << 62) | (uint64_t)localKeep;
      __hip_atomic_store(&desc[vb], d0, __ATOMIC_RELEASE, __HIP_MEMORY_SCOPE_AGENT);
    }
    uint64_t excl = 0;
    if (vb > 0) {
      int wbase = (int)vb - 1;
      for (;;) {
        const int idx = wbase - lane;
        const uint64_t d = (idx >= 0)
            ? __hip_atomic_load(&desc[idx], __ATOMIC_ACQUIRE, __HIP_MEMORY_SCOPE_AGENT)
            : (FL_PRE << 62);
        const uint32_t fl = (uint32_t)(d >> 62);
        const unsigned long long preMask  = __ballot(fl == (uint32_t)FL_PRE);
        const unsigned long long zeroMask = __ballot(fl == 0u);
        if (preMask != 0ull) {
          const int L = __ffsll((long long)preMask) - 1;  // nearest PRE
          if ((zeroMask & ((1ull << L) - 1ull)) == 0ull) {
            uint32_t contrib = (lane <= L) ? (uint32_t)(d & VALMASK) : 0u;
            #pragma unroll
            for (int off = 32; off >= 1; off >>= 1)
              contrib += __shfl_down(contrib, (unsigned)off);
            if (lane == 0) excl += contrib;
            break;
          }
        } else if (zeroMask == 0ull) {
          uint32_t contrib = (uint32_t)(d & VALMASK);
          #pragma unroll
          for (int off = 32; off >= 1; off >>= 1)
            contrib += __shfl_down(contrib, (unsigned)off);
          if (lane == 0) excl += contrib;
          wbase -= 64;
          continue;
        }
        __builtin_amdgcn_s_sleep(1);
      }
    }
    if (lane == 0) {
      sb[1] = (uint32_t)excl;
      __hip_atomic_store(&desc[vb], (FL_PRE << 62) | (excl + (uint64_t)localKeep),
                         __ATOMIC_RELEASE, __HIP_MEMORY_SCOPE_AGENT);
    }
  }
  __syncthreads();

  // phase 2a: dense dump of kept edges [base, base+cnt)
  const uint32_t base = sb[1];
  const uint32_t cnt = localKeep;
  const uint32_t end = base + cnt;
  const uint32_t aStart = (base + 3u) & ~3u;
  const uint32_t aEnd = end & ~3u;
  const uint32_t headEnd = (aStart < end) ? aStart : end;
  for (uint32_t g = base + t; g < headEnd; g += FB_T) {
    out[g] = ldsU[g - base];
    out[NEDGE + g] = ldsI[g - base];
  }
  if (end > aStart) {
    const uint32_t nVec = (aEnd - aStart) >> 2;
    for (uint32_t v = t; v < nVec; v += FB_T) {
      const uint32_t g = aStart + (v << 2);
      const uint32_t l = g - base;
      const int4 vu = make_int4(ldsU[l], ldsU[l + 1], ldsU[l + 2], ldsU[l + 3]);
      const int4 vi = make_int4(ldsI[l], ldsI[l + 1], ldsI[l + 2], ldsI[l + 3]);
      *(int4*)(out + g) = vu;
      *(int4*)(out + NEDGE + g) = vi;
    }
    for (uint32_t g = aEnd + t; g < end; g += FB_T) {
      out[g] = ldsU[g - base];
      out[NEDGE + g] = ldsI[g - base];
    }
  }

  // phase 2b: -1 tail, reverse-indexed
  const uint32_t validEdges =
      (uint32_t)((NEDGE - blockStart) < (int64_t)FB_EDGES ? (NEDGE - blockStart)
                                                          : (int64_t)FB_EDGES);
  const uint32_t dropExcl = (uint32_t)blockStart - base;
  const uint32_t localDrops = validEdges - cnt;
  for (uint32_t j = t; j < localDrops; j += FB_T) {
    const uint32_t slot = (uint32_t)(NEDGE - 1) - (dropExcl + j);
    out[slot] = -1;
    out[NEDGE + slot] = -1;
  }
}

extern "C" void kernel_launch(void* const* d_in, const int* in_sizes, int n_in,
                              void* d_out, int out_size, void* d_ws,
                              size_t ws_size, hipStream_t stream) {
  (void)in_sizes; (void)n_in; (void)out_size; (void)ws_size;
  const int* ei = (const int*)d_in[0];
  int* out = (int*)d_out;
  char* ws = (char*)d_ws;

  uint32_t* hist1 = (uint32_t*)(ws + OFS_HIST1);
  uint32_t* hist2 = (uint32_t*)(ws + OFS_HIST2);
  uint32_t* cnt1  = (uint32_t*)(ws + OFS_CNT1);
  uint64_t* scal  = (uint64_t*)(ws + OFS_SCAL);
  uint32_t* candN  = (uint32_t*)(ws + OFS_SCAL + 24);  // scal[3] low
  uint32_t* ticket = (uint32_t*)(ws + OFS_SCAL + 32);  // scal[4] low
  uint64_t* desc  = (uint64_t*)(ws + OFS_DESC);
  uint32_t* offs1 = (uint32_t*)(ws + OFS_OFFS1);
  uint32_t* bits1 = (uint32_t*)(ws + OFS_BITS1);
  uint32_t* bits2 = (uint32_t*)(ws + OFS_BITS2);
  uint32_t* rank1 = (uint32_t*)(ws + OFS_RANK1);
  uint64_t* sort1 = (uint64_t*)(ws + OFS_SORT1);
  uint64_t* cand  = (uint64_t*)(ws + OFS_CAND);
  uint32_t* dropb = (uint32_t*)(ws + OFS_DROPB);

  hipMemsetAsync(d_ws, 0, ZERO_BYTES, stream);

  k_bits_hist<<<(N_NODES + 255) / 256, 256, 0, stream>>>(bits1, bits2, hist1, hist2);
  k_scan_both<<<2, 1024, 0, stream>>>(hist1, hist2, offs1, scal);
  k_scatter_cand<<<(N_NODES + 255) / 256, 256, 0, stream>>>(
      bits1, bits2, offs1, cnt1, sort1, scal, cand, candN);
  k_rank1_thresh<<<783, 256, 0, stream>>>(bits1, offs1, hist1, sort1, rank1,
                                          cand, candN, scal);
  k_drop<<<(NWORDS_ND + 255) / 256, 256, 0, stream>>>(bits2, rank1, scal, dropb);
  k_fused<<<FB_NB, FB_T, 0, stream>>>(ei, dropb, ticket, desc, out);
}

// Round 4
// 491.391 us; speedup vs baseline: 2.0345x; 2.0345x over previous
//
#include <hip/hip_runtime.h>
#include <stdint.h>

// ---------------------------------------------------------------------------
// NodeDropout: drop-set = jax.random.permutation(key(42), 200000)[:20000]
// (partitionable threefry), keep edge unless BOTH endpoints dropped,
// stable-compact kept edges, -1 tail.
// 3-pass edge compaction: count -> scan -> LDS-staged scatter (dense stores,
// reverse-indexed -1 tail). No cross-XCD sync inside kernels (R3 lesson).
// ---------------------------------------------------------------------------

#define N_NODES   200000
#define N_DROP    20000
#define NEDGE     20000000
#define NBIN      65536
#define NWORDS_ND 6250          // 200000/32

// edge-pass geometry (count & scatter share it)
#define FB_T      256
#define FB_VEC    4
#define FB_IT     4
#define FB_EDGES  (FB_T*FB_VEC*FB_IT)               // 4096
#define FB_NB     ((NEDGE + FB_EDGES - 1)/FB_EDGES) // 4883

// ---- workspace layout (bytes). Zeroed region: [0, ZERO_BYTES) ----
#define OFS_HIST1   0u
#define OFS_HIST2   262144u
#define OFS_CNT1    524288u
#define OFS_SCAL    786432u     // u64[8]: 0=B 1=r 2=T 3=candCount(u32)
#define ZERO_BYTES  786496u
#define OFS_BLKCNT  786496u     // FB_NB u32
#define OFS_BLKOFF  806032u     // FB_NB u32
#define OFS_OFFS1   825568u
#define OFS_BITS1   1087712u
#define OFS_BITS2   1887712u
#define OFS_RANK1   2687712u
#define OFS_SORT1   3487712u
#define OFS_CAND    5087712u    // 4096 u64
#define OFS_DROPB   5120480u    // 6250 u32 node drop bits
// total ~5.15 MB

struct U2pair { uint32_t a, b; };

// Threefry-2x32, 20 rounds — exact JAX/Random123 schedule.
__host__ __device__ constexpr U2pair tf2x32(uint32_t k0, uint32_t k1,
                                            uint32_t x0, uint32_t x1) {
  uint32_t ks[3] = { k0, k1, 0x1BD11BDAu ^ k0 ^ k1 };
  uint32_t v0 = x0 + ks[0];
  uint32_t v1 = x1 + ks[1];
  const int rotA[4] = {13, 15, 26, 6};
  const int rotB[4] = {17, 29, 16, 24};
  for (int i = 0; i < 5; ++i) {
    for (int j = 0; j < 4; ++j) {
      const int r = (i & 1) ? rotB[j] : rotA[j];
      v0 += v1;
      v1 = (v1 << r) | (v1 >> (32 - r));
      v1 ^= v0;
    }
    v0 += ks[(i + 1) % 3];
    v1 += ks[(i + 2) % 3] + (uint32_t)(i + 1);
  }
  return U2pair{v0, v1};
}

// Partitionable key chain from key(42) = (0,42):
//   split: keys[j] = tf(key, 0, j).  carried = keys[0], use1 = keys[1]
//   split #2 on carried: use2 = tf(carried, 0, 1)
constexpr U2pair CARRY1 = tf2x32(0u, 42u, 0u, 0u);
constexpr U2pair USE1   = tf2x32(0u, 42u, 0u, 1u);
constexpr uint32_t UK1A = USE1.a, UK1B = USE1.b;
constexpr U2pair USE2   = tf2x32(CARRY1.a, CARRY1.b, 0u, 1u);
constexpr uint32_t UK2A = USE2.a, UK2B = USE2.b;

// ---------------------------------------------------------------------------
// K1: bits1/bits2 (partitionable: bits[i] = out0^out1 of counter (0,i)) + hists.
__global__ void k_bits_hist(uint32_t* __restrict__ bits1,
                            uint32_t* __restrict__ bits2,
                            uint32_t* __restrict__ hist1,
                            uint32_t* __restrict__ hist2) {
  const int i = blockIdx.x * blockDim.x + threadIdx.x;
  if (i >= N_NODES) return;
  const U2pair r1 = tf2x32(UK1A, UK1B, 0u, (uint32_t)i);
  const U2pair r2 = tf2x32(UK2A, UK2B, 0u, (uint32_t)i);
  const uint32_t b1 = r1.a ^ r1.b;
  const uint32_t b2 = r2.a ^ r2.b;
  bits1[i] = b1;
  bits2[i] = b2;
  atomicAdd(&hist1[b1 >> 16], 1u);
  atomicAdd(&hist2[b2 >> 16], 1u);
}

// K2: dual histogram scan. Block 0: hist1 -> offs1. Block 1: hist2 + findSel.
__global__ __launch_bounds__(1024)
void k_scan_both(const uint32_t* __restrict__ hist1,
                 const uint32_t* __restrict__ hist2,
                 uint32_t* __restrict__ offs1,
                 uint64_t* __restrict__ scal) {
  const uint32_t* hist = (blockIdx.x == 0) ? hist1 : hist2;
  uint32_t* offs       = (blockIdx.x == 0) ? offs1 : nullptr;
  const int findSel    = (blockIdx.x == 0) ? 0 : 1;
  __shared__ uint32_t sums[1024];
  const int t = threadIdx.x;
  uint32_t s = 0;
  for (int j = 0; j < NBIN / 1024; ++j) s += hist[t * (NBIN / 1024) + j];
  sums[t] = s;
  __syncthreads();
  for (int d = 1; d < 1024; d <<= 1) {
    const uint32_t v = sums[t];
    const uint32_t add = (t >= d) ? sums[t - d] : 0u;
    __syncthreads();
    sums[t] = v + add;
    __syncthreads();
  }
  uint32_t run = (t == 0) ? 0u : sums[t - 1];
  for (int j = 0; j < NBIN / 1024; ++j) {
    const int b = t * (NBIN / 1024) + j;
    const uint32_t c = hist[b];
    if (offs) offs[b] = run;
    if (findSel && run <= (uint32_t)(N_DROP - 1) &&
        (uint32_t)(N_DROP - 1) < run + c) {
      scal[0] = (uint64_t)b;
      scal[1] = (uint64_t)((N_DROP - 1) - run);
    }
    run += c;
  }
}

// K3: scatter round-1 composite keys into buckets + gather round-2 candidates.
__global__ void k_scatter_cand(const uint32_t* __restrict__ bits1,
                               const uint32_t* __restrict__ bits2,
                               const uint32_t* __restrict__ offs1,
                               uint32_t* __restrict__ cnt1,
                               uint64_t* __restrict__ sort1,
                               const uint64_t* __restrict__ scal,
                               uint64_t* __restrict__ cand,
                               uint32_t* __restrict__ candCount) {
  const int i = blockIdx.x * blockDim.x + threadIdx.x;
  if (i >= N_NODES) return;
  const uint32_t k = bits1[i];
  const uint32_t b = k >> 16;
  const uint32_t slot = atomicAdd(&cnt1[b], 1u);
  sort1[offs1[b] + slot] = ((uint64_t)k << 32) | (uint32_t)i;

  const uint32_t B = (uint32_t)scal[0];
  const uint32_t k2 = bits2[i];
  if ((k2 >> 16) == B) {
    const uint32_t p = atomicAdd(candCount, 1u);
    if (p < 4096u) cand[p] = ((uint64_t)k2 << 32) | (uint32_t)i;
  }
}

// K4: rank1 (blocks 0..781) + threshold select (block 782).
__global__ void k_rank1_thresh(const uint32_t* __restrict__ bits1,
                               const uint32_t* __restrict__ offs1,
                               const uint32_t* __restrict__ hist1,
                               const uint64_t* __restrict__ sort1,
                               uint32_t* __restrict__ rank1,
                               const uint64_t* __restrict__ cand,
                               const uint32_t* __restrict__ candCount,
                               uint64_t* __restrict__ scal) {
  if (blockIdx.x == 782) {
    if (threadIdx.x != 0) return;
    const uint32_t n = *candCount;
    const uint32_t r = (uint32_t)scal[1];
    uint64_t T = 0;
    for (uint32_t a = 0; a < n; ++a) {
      const uint64_t v = cand[a];
      uint32_t c = 0;
      for (uint32_t b = 0; b < n; ++b) c += (cand[b] < v) ? 1u : 0u;
      if (c == r) { T = v; break; }
    }
    scal[2] = T;
    return;
  }
  const int i = blockIdx.x * blockDim.x + threadIdx.x;
  if (i >= N_NODES) return;
  const uint32_t k = bits1[i];
  const uint32_t b = k >> 16;
  const uint64_t me = ((uint64_t)k << 32) | (uint32_t)i;
  const uint32_t start = offs1[b];
  const uint32_t cnt = hist1[b];
  uint32_t c = 0;
  for (uint32_t s = 0; s < cnt; ++s) c += (sort1[start + s] < me) ? 1u : 0u;
  rank1[i] = start + c;
}

// K5: node drop bits. drop[i] = K2(rank1(i)) <= T.
__global__ void k_drop(const uint32_t* __restrict__ bits2,
                       const uint32_t* __restrict__ rank1,
                       const uint64_t* __restrict__ scal,
                       uint32_t* __restrict__ dropbits) {
  const int w = blockIdx.x * blockDim.x + threadIdx.x;
  if (w >= NWORDS_ND) return;
  const uint64_t T = scal[2];
  uint32_t word = 0;
  #pragma unroll 4
  for (int j = 0; j < 32; ++j) {
    const int i = w * 32 + j;
    const uint32_t jj = rank1[i];
    const uint64_t K2 = ((uint64_t)bits2[jj] << 32) | jj;
    if (K2 <= T) word |= (1u << j);
  }
  dropbits[w] = word;
}

// ---------------------------------------------------------------------------
// K6: per-block keep counts. Barrier-free except the final 4-word reduce.
__global__ __launch_bounds__(FB_T)
void k_count(const int* __restrict__ ei,
             const uint32_t* __restrict__ dropbits,
             uint32_t* __restrict__ blkcnt) {
  const int b = blockIdx.x;
  const int t = threadIdx.x;
  const int64_t blockStart = (int64_t)b * FB_EDGES;
  __shared__ uint32_t wsum[FB_T / 64];
  uint32_t myCount = 0;
  #pragma unroll
  for (int k = 0; k < FB_IT; ++k) {
    const int64_t e = blockStart + (int64_t)(k * (FB_T * FB_VEC) + t * FB_VEC);
    if (e < NEDGE) {
      const int4 u4 = *(const int4*)(ei + e);
      const int4 i4 = *(const int4*)(ei + NEDGE + e);
      const int us[4] = {u4.x, u4.y, u4.z, u4.w};
      const int is_[4] = {i4.x, i4.y, i4.z, i4.w};
      #pragma unroll
      for (int j = 0; j < 4; ++j) {
        const uint32_t du = (dropbits[us[j] >> 5] >> (us[j] & 31)) & 1u;
        uint32_t keep = 1u;
        if (du) keep = 1u - ((dropbits[is_[j] >> 5] >> (is_[j] & 31)) & 1u);
        myCount += keep;
      }
    }
  }
  uint32_t v = myCount;
  #pragma unroll
  for (int d = 32; d >= 1; d >>= 1) v += __shfl_down(v, d);
  if ((t & 63) == 0) wsum[t >> 6] = v;
  __syncthreads();
  if (t == 0) blkcnt[b] = wsum[0] + wsum[1] + wsum[2] + wsum[3];
}

// K7: scan of block counts (FB_NB=4883 fits one 1024-thread block).
#define SB_PER ((FB_NB + 1023) / 1024)   // 5
__global__ __launch_bounds__(1024)
void k_scan_blocks(const uint32_t* __restrict__ blkcnt,
                   uint32_t* __restrict__ blkoff) {
  __shared__ uint32_t sums[1024];
  const int t = threadIdx.x;
  uint32_t loc[SB_PER];
  uint32_t s = 0;
  #pragma unroll
  for (int j = 0; j < SB_PER; ++j) {
    const int idx = t * SB_PER + j;
    const uint32_t c = (idx < FB_NB) ? blkcnt[idx] : 0u;
    loc[j] = c; s += c;
  }
  sums[t] = s;
  __syncthreads();
  for (int d = 1; d < 1024; d <<= 1) {
    const uint32_t v = sums[t];
    const uint32_t add = (t >= d) ? sums[t - d] : 0u;
    __syncthreads();
    sums[t] = v + add;
    __syncthreads();
  }
  uint32_t excl = (t == 0) ? 0u : sums[t - 1];
  #pragma unroll
  for (int j = 0; j < SB_PER; ++j) {
    const int idx = t * SB_PER + j;
    if (idx < FB_NB) blkoff[idx] = excl;
    excl += loc[j];
  }
}

// ---------------------------------------------------------------------------
// K8: stable scatter with LDS staging. Kept edges compacted in LDS, dumped as
// dense aligned int4 stores at blkoff[b]. Dropped edges (-1) written at
// reverse-indexed tail slots NEDGE-1-(dropExcl+j), which tile [n_keep, NEDGE).
__global__ __launch_bounds__(FB_T)
void k_scatter(const int* __restrict__ ei,
               const uint32_t* __restrict__ dropbits,
               const uint32_t* __restrict__ blkoff,
               int* __restrict__ out) {
  __shared__ int ldsU[FB_EDGES];
  __shared__ int ldsI[FB_EDGES];
  __shared__ uint32_t wtot[FB_T / 64];
  const int b = blockIdx.x;
  const int t = threadIdx.x;
  const int lane = t & 63, wid = t >> 6;
  const int64_t blockStart = (int64_t)b * FB_EDGES;

  // phase 1: flags + block-local compaction into LDS
  uint32_t runBase = 0;
  for (int k = 0; k < FB_IT; ++k) {
    const int64_t e = blockStart + (int64_t)(k * (FB_T * FB_VEC) + t * FB_VEC);
    uint32_t flags = 0;
    int us[4] = {0, 0, 0, 0}, is_[4] = {0, 0, 0, 0};
    if (e < NEDGE) {
      const int4 u4 = *(const int4*)(ei + e);
      const int4 i4 = *(const int4*)(ei + NEDGE + e);
      us[0] = u4.x; us[1] = u4.y; us[2] = u4.z; us[3] = u4.w;
      is_[0] = i4.x; is_[1] = i4.y; is_[2] = i4.z; is_[3] = i4.w;
      #pragma unroll
      for (int j = 0; j < 4; ++j) {
        const uint32_t du = (dropbits[us[j] >> 5] >> (us[j] & 31)) & 1u;
        uint32_t keep = 1u;
        if (du) keep = 1u - ((dropbits[is_[j] >> 5] >> (is_[j] & 31)) & 1u);
        flags |= keep << j;
      }
    }
    const uint32_t c = __popc(flags);
    uint32_t incl = c;
    #pragma unroll
    for (int d = 1; d < 64; d <<= 1) {
      const uint32_t o = __shfl_up(incl, (unsigned)d);
      if (lane >= d) incl += o;
    }
    if (lane == 63) wtot[wid] = incl;
    __syncthreads();
    uint32_t wpref = 0, tot = 0;
    #pragma unroll
    for (int w2 = 0; w2 < FB_T / 64; ++w2) {
      const uint32_t v = wtot[w2];
      if (w2 < wid) wpref += v;
      tot += v;
    }
    uint32_t pos = runBase + wpref + incl - c;
    #pragma unroll
    for (int j = 0; j < 4; ++j) {
      if ((flags >> j) & 1u) { ldsU[pos] = us[j]; ldsI[pos] = is_[j]; ++pos; }
    }
    runBase += tot;
    __syncthreads();
  }
  const uint32_t cnt = runBase;

  // phase 2a: dense dump of kept edges [base, base+cnt)
  const uint32_t base = blkoff[b];
  const uint32_t end = base + cnt;
  const uint32_t aStart = (base + 3u) & ~3u;
  const uint32_t aEnd = end & ~3u;
  const uint32_t headEnd = (aStart < end) ? aStart : end;
  for (uint32_t g = base + t; g < headEnd; g += FB_T) {
    out[g] = ldsU[g - base];
    out[NEDGE + g] = ldsI[g - base];
  }
  if (end > aStart) {
    const uint32_t nVec = (aEnd - aStart) >> 2;
    for (uint32_t v = t; v < nVec; v += FB_T) {
      const uint32_t g = aStart + (v << 2);
      const uint32_t l = g - base;
      const int4 vu = make_int4(ldsU[l], ldsU[l + 1], ldsU[l + 2], ldsU[l + 3]);
      const int4 vi = make_int4(ldsI[l], ldsI[l + 1], ldsI[l + 2], ldsI[l + 3]);
      *(int4*)(out + g) = vu;
      *(int4*)(out + NEDGE + g) = vi;
    }
    for (uint32_t g = aEnd + t; g < end; g += FB_T) {
      out[g] = ldsU[g - base];
      out[NEDGE + g] = ldsI[g - base];
    }
  }

  // phase 2b: -1 tail, reverse-indexed
  const uint32_t validEdges =
      (uint32_t)((NEDGE - blockStart) < (int64_t)FB_EDGES ? (NEDGE - blockStart)
                                                          : (int64_t)FB_EDGES);
  const uint32_t dropExcl = (uint32_t)blockStart - base;
  const uint32_t localDrops = validEdges - cnt;
  for (uint32_t j = t; j < localDrops; j += FB_T) {
    const uint32_t slot = (uint32_t)(NEDGE - 1) - (dropExcl + j);
    out[slot] = -1;
    out[NEDGE + slot] = -1;
  }
}

extern "C" void kernel_launch(void* const* d_in, const int* in_sizes, int n_in,
                              void* d_out, int out_size, void* d_ws,
                              size_t ws_size, hipStream_t stream) {
  (void)in_sizes; (void)n_in; (void)out_size; (void)ws_size;
  const int* ei = (const int*)d_in[0];
  int* out = (int*)d_out;
  char* ws = (char*)d_ws;

  uint32_t* hist1 = (uint32_t*)(ws + OFS_HIST1);
  uint32_t* hist2 = (uint32_t*)(ws + OFS_HIST2);
  uint32_t* cnt1  = (uint32_t*)(ws + OFS_CNT1);
  uint64_t* scal  = (uint64_t*)(ws + OFS_SCAL);
  uint32_t* candN  = (uint32_t*)(ws + OFS_SCAL + 24);  // scal[3] low
  uint32_t* blkcnt = (uint32_t*)(ws + OFS_BLKCNT);
  uint32_t* blkoff = (uint32_t*)(ws + OFS_BLKOFF);
  uint32_t* offs1 = (uint32_t*)(ws + OFS_OFFS1);
  uint32_t* bits1 = (uint32_t*)(ws + OFS_BITS1);
  uint32_t* bits2 = (uint32_t*)(ws + OFS_BITS2);
  uint32_t* rank1 = (uint32_t*)(ws + OFS_RANK1);
  uint64_t* sort1 = (uint64_t*)(ws + OFS_SORT1);
  uint64_t* cand  = (uint64_t*)(ws + OFS_CAND);
  uint32_t* dropb = (uint32_t*)(ws + OFS_DROPB);

  hipMemsetAsync(d_ws, 0, ZERO_BYTES, stream);

  k_bits_hist<<<(N_NODES + 255) / 256, 256, 0, stream>>>(bits1, bits2, hist1, hist2);
  k_scan_both<<<2, 1024, 0, stream>>>(hist1, hist2, offs1, scal);
  k_scatter_cand<<<(N_NODES + 255) / 256, 256, 0, stream>>>(
      bits1, bits2, offs1, cnt1, sort1, scal, cand, candN);
  k_rank1_thresh<<<783, 256, 0, stream>>>(bits1, offs1, hist1, sort1, rank1,
                                          cand, candN, scal);
  k_drop<<<(NWORDS_ND + 255) / 256, 256, 0, stream>>>(bits2, rank1, scal, dropb);
  k_count<<<FB_NB, FB_T, 0, stream>>>(ei, dropb, blkcnt);
  k_scan_blocks<<<1, 1024, 0, stream>>>(blkcnt, blkoff);
  k_scatter<<<FB_NB, FB_T, 0, stream>>>(ei, dropb, blkoff, out);
}